// Round 6
// baseline (463.296 us; speedup 1.0000x reference)
//
#include <hip/hip_runtime.h>
#include <hip/hip_bf16.h>

// ---------------------------------------------------------------------------
// ATTEfficient: s = tanh(X@Ww^T + bw)@v ; segment softmax ; att-pool ; MLP head
// X: [32768,1280] f32, Ww: [1280,1280], v: [1280], W1: [512,1280], W2: [1,512]
// ---------------------------------------------------------------------------

#define TOTAL_ROWS 32768
#define DIM 1280
#define NSEG 128
#define DHEAD 512
#define NKT 20   // K tiles of 64 along DIM
#define NPART 4  // softpool row-parts per segment

typedef _Float16 f16x8 __attribute__((ext_vector_type(8)));
typedef _Float16 f16x4 __attribute__((ext_vector_type(4)));
typedef float f32x4 __attribute__((ext_vector_type(4)));

// ---- workspace layout (bytes) ----
#define OFF_XH   0                            // 32768*1280*2 = 83886080
#define OFF_WH   83886080                     // 1280*1280*2  = 3276800
#define OFF_S    87162880                     // 32768*4      = 131072
#define OFF_SEG  87425024                     // 132*4 -> pad 1024
#define OFF_POOL 87426048                     // 128*1280*4   = 655360
#define OFF_H    88081408                     // 128*512*4    = 262144
// pooled_parts[4][128][1280] f32 = 2621440 B aliases the Wh region (Wh is dead
// after gemm_s_kernel; softpool runs strictly after it on the same stream).
#define OFF_PP   OFF_WH

__device__ __forceinline__ void load_lds16(const void* g, void* l) {
  __builtin_amdgcn_global_load_lds(
      (const __attribute__((address_space(1))) unsigned int*)g,
      (__attribute__((address_space(3))) unsigned int*)l, 16, 0, 0);
}

__device__ __forceinline__ float tanh_fast(float x) {
  float e = __expf(2.0f * x);
  return 1.0f - 2.0f * __builtin_amdgcn_rcpf(e + 1.0f);
}

// ---- f32->f16 cvt for X and W + buffer init + segstart, one launch ----
__global__ void cvt_init_kernel(const float* __restrict__ a, _Float16* __restrict__ oa,
                                int na8, const float* __restrict__ b,
                                _Float16* __restrict__ ob, int nb8,
                                const int* __restrict__ sid,
                                int* __restrict__ segstart, float* __restrict__ s) {
  int i = blockIdx.x * blockDim.x + threadIdx.x;
  // init duties (ws is 0xAA-poisoned before every launch)
  if (i < TOTAL_ROWS) {
    s[i] = 0.f;
    int sg = sid[i];
    if (i == 0) segstart[0] = 0;
    else if (sid[i - 1] != sg) segstart[sg] = i;
    if (i == TOTAL_ROWS - 1) segstart[sg + 1] = TOTAL_ROWS;
  }
  // conversion duties
  const float* in;
  _Float16* out;
  int idx;
  if (i < na8) {
    in = a; out = oa; idx = i;
  } else {
    idx = i - na8;
    if (idx >= nb8) return;
    in = b; out = ob;
  }
  const float4* p = (const float4*)in + (size_t)idx * 2;
  float4 u0 = p[0], u1 = p[1];
  f16x8 h;
  h[0] = (_Float16)u0.x; h[1] = (_Float16)u0.y;
  h[2] = (_Float16)u0.z; h[3] = (_Float16)u0.w;
  h[4] = (_Float16)u1.x; h[5] = (_Float16)u1.y;
  h[6] = (_Float16)u1.z; h[7] = (_Float16)u1.w;
  *((f16x8*)out + idx) = h;
}

// ---------------------------------------------------------------------------
// fused GEMM + tanh + dot-with-v:  s[i] += sum_j tanh(X_i.W_j + bw_j) v_j
// 256x256 tile, BK=64, 8 waves (2Mx4N, 128x64 each), 128 KiB double-buffered
// LDS.  R6: ONE barrier per K-tile.  Both A(t+1) and B(t+1) stage at
// distance 1 into buf P^1 (readers of P^1 finished before tile t-1's end
// barrier -> WAR-safe anywhere in tile t, no mid-tile barrier needed).
// Staging loads issue at TILE START, so the tile-end vmcnt(0) retires
// already-landed loads (HBM ~900 cyc << tile ~4000 cyc) -- drain is free.
// Fragment ds_reads are interleaved 2x2-blockwise with the 64 MFMAs so the
// first MFMA depends on only 8 ds_reads and later reads hide under MFMA.
//
// Per tile t (buf P = t&1):
//   stage A(t+1),B(t+1) -> buf P^1          [8 gload_lds]
//   read b0,b1,a0,a1; MFMA r0-1 x n0-1      [8 reads, 8 MFMA]
//   read b2,b3;       MFMA r0-1 x n2-3      [4 reads, 8 MFMA]
//   read a2,a3;       MFMA r2-3 x n0-3      [4 reads, 16 MFMA]
//   read a4,a5;       MFMA r4-5 x n0-3      [4 reads, 16 MFMA]
//   read a6,a7;       MFMA r6-7 x n0-3      [4 reads, 16 MFMA]
//   vmcnt(0); sched_barrier(0); BAR
// Invariants: wave's ds_reads of P complete before its dependent MFMAs
// (compiler-counted lgkmcnt); MFMAs pinned before BAR by sched_barrier(0);
// BAR publishes the landed P^1 stages for tile t+1.
// ---------------------------------------------------------------------------
__global__ __launch_bounds__(512, 2) void gemm_s_kernel(
    const _Float16* __restrict__ X, const _Float16* __restrict__ W,
    const float* __restrict__ v, const float* __restrict__ bw,
    float* __restrict__ s) {
  __shared__ _Float16 As[2][2][8192];   // [buf][half][128 rows * 64 f16], 64 KB
  __shared__ _Float16 Bs[2][2][8192];   // 64 KB

  const int rowBase = blockIdx.x * 256;
  const int jBase = blockIdx.y * 256;
  const int t = threadIdx.x;
  const int lane = t & 63;
  const int w = t >> 6;        // wave 0..7
  const int wm = w >> 2;       // 0..1 : M half (rows wm*128..)
  const int wn = w & 3;        // 0..3 : N quarter (cols wn*64..)
  const int lm = lane & 15;
  const int kc = lane >> 4;
  const int bh = wn >> 1;      // which B half this wave reads

  // staging: slot l = L*512 + w*64 + lane holds 16B chunk g of row
  // half*128 + L*64 + w*8 + (lane>>3);  g = ((lane&7) - subrow) & 7
  const int subrow = lane >> 3;
  const int g = ((lane & 7) - subrow) & 7;
  const _Float16* gA = X + (size_t)(rowBase + w * 8 + subrow) * DIM + g * 8;
  const _Float16* gB = W + (size_t)(jBase + w * 8 + subrow) * DIM + g * 8;

  // ds_read fragment offsets (f16 units); row%8 == lm%8 makes the rotate
  // swizzle mt/nt-invariant: full offset = base[ks] + frag*1024
  int aOff[2], bOff[2];
#pragma unroll
  for (int ks = 0; ks < 2; ++ks) {
    int swz = ((ks * 4 + kc + lm) & 7) * 8;
    aOff[ks] = lm * 64 + swz;
    bOff[ks] = ((wn & 1) * 64 + lm) * 64 + swz;
  }

  f32x4 acc[8][4];
  const f32x4 zero = {0.f, 0.f, 0.f, 0.f};
#pragma unroll
  for (int i = 0; i < 8; ++i)
#pragma unroll
    for (int j = 0; j < 4; ++j) acc[i][j] = zero;

  f16x8 a[4][2], b[4][2];

#define STAGE_A(BUF, HALF, TT) do { \
    const _Float16* _src = gA + (size_t)(HALF) * 128 * DIM + (size_t)(TT) * 64; \
    load_lds16(_src, &As[BUF][HALF][w * 512]); \
    load_lds16(_src + 64 * DIM, &As[BUF][HALF][4096 + w * 512]); \
  } while (0)
#define STAGE_B(BUF, HALF, TT) do { \
    const _Float16* _src = gB + (size_t)(HALF) * 128 * DIM + (size_t)(TT) * 64; \
    load_lds16(_src, &Bs[BUF][HALF][w * 512]); \
    load_lds16(_src + 64 * DIM, &Bs[BUF][HALF][4096 + w * 512]); \
  } while (0)

#define READ_A1(BUF, SLOT, MT) do { \
    _Pragma("unroll") for (int ks = 0; ks < 2; ++ks) \
      a[SLOT][ks] = *(const f16x8*)&As[BUF][wm][aOff[ks] + (MT) * 1024]; \
  } while (0)
#define READ_B1(BUF, NT) do { \
    _Pragma("unroll") for (int ks = 0; ks < 2; ++ks) \
      b[NT][ks] = *(const f16x8*)&Bs[BUF][bh][bOff[ks] + (NT) * 1024]; \
  } while (0)
// 8 MFMAs: rows {R0,R1} (fragment slots S0,S1) x cols {N0,N1}
#define MFMA_Q(S0, S1, R0, R1, N0, N1) do { \
    __builtin_amdgcn_s_setprio(1); \
    _Pragma("unroll") for (int ks = 0; ks < 2; ++ks) { \
      acc[R0][N0] = __builtin_amdgcn_mfma_f32_16x16x32_f16( \
          a[S0][ks], b[N0][ks], acc[R0][N0], 0, 0, 0); \
      acc[R0][N1] = __builtin_amdgcn_mfma_f32_16x16x32_f16( \
          a[S0][ks], b[N1][ks], acc[R0][N1], 0, 0, 0); \
      acc[R1][N0] = __builtin_amdgcn_mfma_f32_16x16x32_f16( \
          a[S1][ks], b[N0][ks], acc[R1][N0], 0, 0, 0); \
      acc[R1][N1] = __builtin_amdgcn_mfma_f32_16x16x32_f16( \
          a[S1][ks], b[N1][ks], acc[R1][N1], 0, 0, 0); \
    } \
    __builtin_amdgcn_s_setprio(0); \
  } while (0)

#define CFENCE asm volatile("" ::: "memory")
#define WAIT_VM0 asm volatile("s_waitcnt vmcnt(0)" ::: "memory")
#define BAR __builtin_amdgcn_s_barrier()
#define SCHED0 __builtin_amdgcn_sched_barrier(0)

#define KTILE(BUF, SA, SB, TAILWAIT) do { \
    CFENCE; \
    SA; SB; \
    READ_B1(BUF, 0); READ_B1(BUF, 1); \
    READ_A1(BUF, 0, 0); READ_A1(BUF, 1, 1); \
    MFMA_Q(0, 1, 0, 1, 0, 1); \
    READ_B1(BUF, 2); READ_B1(BUF, 3); \
    MFMA_Q(0, 1, 0, 1, 2, 3); \
    READ_A1(BUF, 2, 2); READ_A1(BUF, 3, 3); \
    MFMA_Q(2, 3, 2, 3, 0, 1); \
    MFMA_Q(2, 3, 2, 3, 2, 3); \
    READ_A1(BUF, 0, 4); READ_A1(BUF, 1, 5); \
    MFMA_Q(0, 1, 4, 5, 0, 1); \
    MFMA_Q(0, 1, 4, 5, 2, 3); \
    READ_A1(BUF, 2, 6); READ_A1(BUF, 3, 7); \
    MFMA_Q(2, 3, 6, 7, 0, 1); \
    MFMA_Q(2, 3, 6, 7, 2, 3); \
    TAILWAIT; SCHED0; BAR; \
  } while (0)

  // prologue: stage tile0 (A0,B0) = 8 loads; drain; publish
  STAGE_A(0, 0, 0); STAGE_A(0, 1, 0);
  STAGE_B(0, 0, 0); STAGE_B(0, 1, 0);
  WAIT_VM0;
  BAR;

  for (int kt = 0; kt < NKT - 2; kt += 2) {
    KTILE(0,
          { STAGE_A(1, 0, kt + 1); STAGE_A(1, 1, kt + 1); },
          { STAGE_B(1, 0, kt + 1); STAGE_B(1, 1, kt + 1); },
          WAIT_VM0);
    KTILE(1,
          { STAGE_A(0, 0, kt + 2); STAGE_A(0, 1, kt + 2); },
          { STAGE_B(0, 0, kt + 2); STAGE_B(0, 1, kt + 2); },
          WAIT_VM0);
  }
  // tile 18: stage tile 19
  KTILE(0,
        { STAGE_A(1, 0, NKT - 1); STAGE_A(1, 1, NKT - 1); },
        { STAGE_B(1, 0, NKT - 1); STAGE_B(1, 1, NKT - 1); },
        WAIT_VM0);
  // tile 19: no staging, nothing in flight
  KTILE(1, (void)0, (void)0, (void)0);

#undef KTILE
#undef STAGE_A
#undef STAGE_B
#undef READ_A1
#undef READ_B1
#undef MFMA_Q

  // epilogue: C/D layout col=lane&15, row=(lane>>4)*4+reg
  const int colBase = jBase + wn * 64 + lm;
  float vv[4], bb[4];
#pragma unroll
  for (int nt = 0; nt < 4; ++nt) {
    int j = colBase + nt * 16;
    vv[nt] = v[j];
    bb[nt] = bw[j];
  }
  const int gq = lane >> 4;
#pragma unroll
  for (int mt = 0; mt < 8; ++mt) {
#pragma unroll
    for (int r = 0; r < 4; ++r) {
      float sumv = 0.f;
#pragma unroll
      for (int nt = 0; nt < 4; ++nt)
        sumv += tanh_fast(acc[mt][nt][r] + bb[nt]) * vv[nt];
      sumv += __shfl_xor(sumv, 1);
      sumv += __shfl_xor(sumv, 2);
      sumv += __shfl_xor(sumv, 4);
      sumv += __shfl_xor(sumv, 8);
      if (lm == 0) {
        int row = rowBase + wm * 128 + mt * 16 + gq * 4 + r;
        atomicAdd(&s[row], sumv);
      }
    }
  }
}

// ---- fused softmax + attention pooling ----
// grid (128 segs, 4 row-parts), block 320. Each block recomputes the segment
// softmax stats (m, z) from s (<=448 L2-hot floats), then pools its row part
// with att computed on the fly.  Partials go to pooled_parts[part] with
// plain float4 stores (no atomics); fold_kernel sums the 4 parts.
__global__ void softpool_kernel(const _Float16* __restrict__ F,
                                const float* __restrict__ s,
                                const int* __restrict__ segstart,
                                float* __restrict__ pooledp) {
  int seg = blockIdx.x, part = blockIdx.y;
  int st = segstart[seg], en = segstart[seg + 1];
  int t = threadIdx.x;
  __shared__ float redm[5], redz[5];
  float m = -1e30f;
  for (int i = st + t; i < en; i += 320) m = fmaxf(m, s[i]);
  for (int d = 1; d < 64; d <<= 1) m = fmaxf(m, __shfl_xor(m, d));
  if ((t & 63) == 0) redm[t >> 6] = m;
  __syncthreads();
  m = fmaxf(fmaxf(fmaxf(redm[0], redm[1]), fmaxf(redm[2], redm[3])), redm[4]);
  float z = 0.f;
  for (int i = st + t; i < en; i += 320) z += __expf(s[i] - m);
  for (int d = 1; d < 64; d <<= 1) z += __shfl_xor(z, d);
  if ((t & 63) == 0) redz[t >> 6] = z;
  __syncthreads();
  z = redz[0] + redz[1] + redz[2] + redz[3] + redz[4];
  float rz = 1.0f / z;

  int len = en - st;
  int chunk = (len + NPART - 1) / NPART;
  int r0 = st + chunk * part;
  int r1 = min(en, r0 + chunk);
  float acc[4] = {0.f, 0.f, 0.f, 0.f};
  int r = r0;
  for (; r + 2 <= r1; r += 2) {
    float a0 = __expf(s[r] - m) * rz;
    float a1 = __expf(s[r + 1] - m) * rz;
    f16x4 f0 = ((const f16x4*)(F + (size_t)r * DIM))[t];
    f16x4 f1 = ((const f16x4*)(F + (size_t)(r + 1) * DIM))[t];
#pragma unroll
    for (int c = 0; c < 4; ++c) {
      acc[c] = fmaf(a0, (float)f0[c], acc[c]);
      acc[c] = fmaf(a1, (float)f1[c], acc[c]);
    }
  }
  if (r < r1) {
    float a0 = __expf(s[r] - m) * rz;
    f16x4 f0 = ((const f16x4*)(F + (size_t)r * DIM))[t];
#pragma unroll
    for (int c = 0; c < 4; ++c) acc[c] = fmaf(a0, (float)f0[c], acc[c]);
  }
  float4 o;
  o.x = acc[0]; o.y = acc[1]; o.z = acc[2]; o.w = acc[3];
  *(float4*)(pooledp + ((size_t)part * NSEG + seg) * DIM + t * 4) = o;
}

// ---- fold the 4 softpool partials: pooled = sum_p pooled_parts[p] ----
__global__ void fold_kernel(const float* __restrict__ pp,
                            float* __restrict__ pooled) {
  int i = blockIdx.x * 256 + threadIdx.x;   // over NSEG*DIM = 163840
  pooled[i] = pp[i] + pp[i + NSEG * DIM] + pp[i + 2 * NSEG * DIM] +
              pp[i + 3 * NSEG * DIM];
}

// ---- head layer 1: h = relu(pooled @ W1^T + b1), [128,512] ----
__global__ void head1_kernel(const float* __restrict__ pooled,
                             const float* __restrict__ W1,
                             const float* __restrict__ b1, float* __restrict__ h) {
  int og = blockIdx.x, sg = blockIdx.y;
  __shared__ float Wt[16 * 65];
  __shared__ float Pt[32 * 65];
  int t = threadIdx.x;
  int tx = t & 15, ty = t >> 4;
  float acc0 = 0.f, acc1 = 0.f;
  for (int kcc = 0; kcc < 20; ++kcc) {
    __syncthreads();
#pragma unroll
    for (int u = 0; u < 4; ++u) {
      int lin = t + 256 * u;
      int o = lin >> 6, kk = lin & 63;
      Wt[o * 65 + kk] = W1[(size_t)(og * 16 + o) * DIM + kcc * 64 + kk];
    }
#pragma unroll
    for (int u = 0; u < 8; ++u) {
      int lin = t + 256 * u;
      int ss = lin >> 6, kk = lin & 63;
      Pt[ss * 65 + kk] = pooled[(size_t)(sg * 32 + ss) * DIM + kcc * 64 + kk];
    }
    __syncthreads();
#pragma unroll
    for (int kk = 0; kk < 64; ++kk) {
      float wv = Wt[tx * 65 + kk];
      acc0 = fmaf(Pt[ty * 65 + kk], wv, acc0);
      acc1 = fmaf(Pt[(ty + 16) * 65 + kk], wv, acc1);
    }
  }
  int o = og * 16 + tx;
  float bias = b1[o];
  h[(size_t)(sg * 32 + ty) * DHEAD + o] = fmaxf(acc0 + bias, 0.f);
  h[(size_t)(sg * 32 + ty + 16) * DHEAD + o] = fmaxf(acc1 + bias, 0.f);
}

// ---- head layer 2: out[seg] = relu_h[seg] . W2 + b2 ----
__global__ void head2_kernel(const float* __restrict__ h,
                             const float* __restrict__ W2,
                             const float* __restrict__ b2, float* __restrict__ out) {
  int seg = blockIdx.x;
  int t = threadIdx.x;
  float val = h[(size_t)seg * DHEAD + t] * W2[t] +
              h[(size_t)seg * DHEAD + t + 256] * W2[t + 256];
  for (int d = 1; d < 64; d <<= 1) val += __shfl_xor(val, d);
  __shared__ float red[4];
  if ((t & 63) == 0) red[t >> 6] = val;
  __syncthreads();
  if (t == 0) out[seg] = red[0] + red[1] + red[2] + red[3] + b2[0];
}

extern "C" void kernel_launch(void* const* d_in, const int* in_sizes, int n_in,
                              void* d_out, int out_size, void* d_ws, size_t ws_size,
                              hipStream_t stream) {
  const float* features = (const float*)d_in[0];
  const float* Ww = (const float*)d_in[1];
  const float* bw = (const float*)d_in[2];
  const float* v = (const float*)d_in[3];
  const float* W1 = (const float*)d_in[4];
  const float* b1 = (const float*)d_in[5];
  const float* W2 = (const float*)d_in[6];
  const float* b2 = (const float*)d_in[7];
  const int* segids = (const int*)d_in[8];
  float* out = (float*)d_out;

  char* ws = (char*)d_ws;
  _Float16* Xh = (_Float16*)(ws + OFF_XH);
  _Float16* Wh = (_Float16*)(ws + OFF_WH);
  float* s = (float*)(ws + OFF_S);
  int* segstart = (int*)(ws + OFF_SEG);
  float* pooled = (float*)(ws + OFF_POOL);
  float* pooledp = (float*)(ws + OFF_PP);   // aliases Wh (dead after gemm)
  float* h = (float*)(ws + OFF_H);

  const int na8 = TOTAL_ROWS * DIM / 8;   // 5242880
  const int nb8 = DIM * DIM / 8;          // 204800
  cvt_init_kernel<<<(na8 + nb8 + 255) / 256, 256, 0, stream>>>(
      features, Xh, na8, Ww, Wh, nb8, segids, segstart, s);

  dim3 ggrid(TOTAL_ROWS / 256, DIM / 256);   // (128, 5)
  gemm_s_kernel<<<ggrid, 512, 0, stream>>>(Xh, Wh, v, bw, s);

  softpool_kernel<<<dim3(NSEG, NPART), 320, 0, stream>>>(Xh, s, segstart, pooledp);
  fold_kernel<<<NSEG * DIM / 256, 256, 0, stream>>>(pooledp, pooled);
  head1_kernel<<<dim3(32, 4), 256, 0, stream>>>(pooled, W1, b1, h);
  head2_kernel<<<NSEG, 256, 0, stream>>>(h, W2, b2, out);
}

// Round 7
// 451.223 us; speedup vs baseline: 1.0268x; 1.0268x over previous
//
#include <hip/hip_runtime.h>
#include <hip/hip_bf16.h>

// ---------------------------------------------------------------------------
// ATTEfficient: s = tanh(X@Ww^T + bw)@v ; segment softmax ; att-pool ; MLP head
// X: [32768,1280] f32, Ww: [1280,1280], v: [1280], W1: [512,1280], W2: [1,512]
// ---------------------------------------------------------------------------

#define TOTAL_ROWS 32768
#define DIM 1280
#define NSEG 128
#define DHEAD 512
#define NKT 20   // K tiles of 64 along DIM
#define NPART 4  // softpool row-parts per segment

typedef _Float16 f16x8 __attribute__((ext_vector_type(8)));
typedef _Float16 f16x4 __attribute__((ext_vector_type(4)));
typedef float f32x4 __attribute__((ext_vector_type(4)));

// ---- workspace layout (bytes) ----
#define OFF_XH   0                            // 32768*1280*2 = 83886080
#define OFF_WH   83886080                     // 1280*1280*2  = 3276800
#define OFF_S    87162880                     // 32768*4      = 131072
#define OFF_SEG  87425024                     // 132*4 -> pad 1024
#define OFF_POOL 87426048                     // 128*1280*4   = 655360
#define OFF_H    88081408                     // 128*512*4    = 262144
// pooled_parts[4][128][1280] f32 = 2621440 B aliases the Wh region (Wh is dead
// after gemm_s_kernel; softpool runs strictly after it on the same stream).
#define OFF_PP   OFF_WH

__device__ __forceinline__ void load_lds16(const void* g, void* l) {
  __builtin_amdgcn_global_load_lds(
      (const __attribute__((address_space(1))) unsigned int*)g,
      (__attribute__((address_space(3))) unsigned int*)l, 16, 0, 0);
}

__device__ __forceinline__ float tanh_fast(float x) {
  float e = __expf(2.0f * x);
  return 1.0f - 2.0f * __builtin_amdgcn_rcpf(e + 1.0f);
}

// ---- f32->f16 cvt for X and W + buffer init + segstart, one launch ----
__global__ void cvt_init_kernel(const float* __restrict__ a, _Float16* __restrict__ oa,
                                int na8, const float* __restrict__ b,
                                _Float16* __restrict__ ob, int nb8,
                                const int* __restrict__ sid,
                                int* __restrict__ segstart, float* __restrict__ s) {
  int i = blockIdx.x * blockDim.x + threadIdx.x;
  // init duties (ws is 0xAA-poisoned before every launch)
  if (i < TOTAL_ROWS) {
    s[i] = 0.f;
    int sg = sid[i];
    if (i == 0) segstart[0] = 0;
    else if (sid[i - 1] != sg) segstart[sg] = i;
    if (i == TOTAL_ROWS - 1) segstart[sg + 1] = TOTAL_ROWS;
  }
  // conversion duties
  const float* in;
  _Float16* out;
  int idx;
  if (i < na8) {
    in = a; out = oa; idx = i;
  } else {
    idx = i - na8;
    if (idx >= nb8) return;
    in = b; out = ob;
  }
  const float4* p = (const float4*)in + (size_t)idx * 2;
  float4 u0 = p[0], u1 = p[1];
  f16x8 h;
  h[0] = (_Float16)u0.x; h[1] = (_Float16)u0.y;
  h[2] = (_Float16)u0.z; h[3] = (_Float16)u0.w;
  h[4] = (_Float16)u1.x; h[5] = (_Float16)u1.y;
  h[6] = (_Float16)u1.z; h[7] = (_Float16)u1.w;
  *((f16x8*)out + idx) = h;
}

// ---------------------------------------------------------------------------
// fused GEMM + tanh + dot-with-v:  s[i] += sum_j tanh(X_i.W_j + bw_j) v_j
// 256x256 tile, BK=64, 8 waves (2Mx4N, 128x64 each), 2 barriers/K-tile.
// R7: BOTH operands stage at distance 2.  A rotates through a TRIPLE buffer
// As[3] (A(t+2) -> As[(t+2)%3]: never the buf being read nor the next; its
// last readers finished before tile t-1's end barrier -> WAR-safe with no
// extra sync).  B stays dist-2 double-buffered behind the mid barrier
// (B(t+2) -> Bs[t%2], issued after BAR_mid when all Bs[t%2] reads are done).
// Tile-end wait is vmcnt(8): every load gets >=2 full tiles (~10k cyc) to
// land, so the wait never blocks (R6 showed vmcnt(0) on same-tile loads
// stalls; R5's A-at-dist-1 vmcnt(4) was the residual exposure).
// LDS = 3*32K (A) + 2*32K (B) = 160 KiB exactly.  Loop unrolled x6
// (lcm(3,2)) so buffer indices are compile-time.
//
// Per tile t (BA = t%3, BB = t%2):
//   alpha: SA: stage A(t+2)->As[(t+2)%3] [4 issues]
//          read b0-3, a0,a1; MFMA r0 | read a2 | r1 | read a3 | r2 | r3
//          sched_barrier(0); BAR_mid
//   beta : SB: stage B(t+2)->Bs[t%2]     [4 issues]
//          read a4,a5; MFMA r4 | read a6 | r5 | read a7 | r6 | r7
//          vmcnt(8); sched_barrier(0); BAR_end
// vmcnt(8) at tile end: in-flight = A(t+1),B(t+1) [8, from t-1] +
// A(t+2),B(t+2) [8, from t] -> retires the t-1 batch (in-order), leaves 8.
// ---------------------------------------------------------------------------
__global__ __launch_bounds__(512, 2) void gemm_s_kernel(
    const _Float16* __restrict__ X, const _Float16* __restrict__ W,
    const float* __restrict__ v, const float* __restrict__ bw,
    float* __restrict__ s) {
  __shared__ _Float16 As[3][2][8192];   // 96 KB: 3 bufs x [half][128r x 64 f16]
  __shared__ _Float16 Bs[2][2][8192];   // 64 KB

  const int rowBase = blockIdx.x * 256;
  const int jBase = blockIdx.y * 256;
  const int t = threadIdx.x;
  const int lane = t & 63;
  const int w = t >> 6;        // wave 0..7
  const int wm = w >> 2;       // 0..1 : M half (rows wm*128..)
  const int wn = w & 3;        // 0..3 : N quarter (cols wn*64..)
  const int lm = lane & 15;
  const int kc = lane >> 4;
  const int bh = wn >> 1;      // which B half this wave reads

  // staging: slot l = L*512 + w*64 + lane holds 16B chunk g of row
  // half*128 + L*64 + w*8 + (lane>>3);  g = ((lane&7) - subrow) & 7
  const int subrow = lane >> 3;
  const int g = ((lane & 7) - subrow) & 7;
  const _Float16* gA = X + (size_t)(rowBase + w * 8 + subrow) * DIM + g * 8;
  const _Float16* gB = W + (size_t)(jBase + w * 8 + subrow) * DIM + g * 8;

  // ds_read fragment offsets (f16 units); row%8 == lm%8 makes the rotate
  // swizzle mt/nt-invariant: full offset = base[ks] + frag*1024
  int aOff[2], bOff[2];
#pragma unroll
  for (int ks = 0; ks < 2; ++ks) {
    int swz = ((ks * 4 + kc + lm) & 7) * 8;
    aOff[ks] = lm * 64 + swz;
    bOff[ks] = ((wn & 1) * 64 + lm) * 64 + swz;
  }

  f32x4 acc[8][4];
  const f32x4 zero = {0.f, 0.f, 0.f, 0.f};
#pragma unroll
  for (int i = 0; i < 8; ++i)
#pragma unroll
    for (int j = 0; j < 4; ++j) acc[i][j] = zero;

  f16x8 a[4][2], b[4][2];

#define STAGE_A(BUF, HALF, TT) do { \
    const _Float16* _src = gA + (size_t)(HALF) * 128 * DIM + (size_t)(TT) * 64; \
    load_lds16(_src, &As[BUF][HALF][w * 512]); \
    load_lds16(_src + 64 * DIM, &As[BUF][HALF][4096 + w * 512]); \
  } while (0)
#define STAGE_B(BUF, HALF, TT) do { \
    const _Float16* _src = gB + (size_t)(HALF) * 128 * DIM + (size_t)(TT) * 64; \
    load_lds16(_src, &Bs[BUF][HALF][w * 512]); \
    load_lds16(_src + 64 * DIM, &Bs[BUF][HALF][4096 + w * 512]); \
  } while (0)
#define SA2(DBUF, TT) do { STAGE_A(DBUF, 0, TT); STAGE_A(DBUF, 1, TT); } while (0)
#define SB2(DBUF, TT) do { STAGE_B(DBUF, 0, TT); STAGE_B(DBUF, 1, TT); } while (0)

#define READ_A1(BA, SLOT, MT) do { \
    _Pragma("unroll") for (int ks = 0; ks < 2; ++ks) \
      a[SLOT][ks] = *(const f16x8*)&As[BA][wm][aOff[ks] + (MT) * 1024]; \
  } while (0)
#define READ_B(BB) do { \
    _Pragma("unroll") for (int nt = 0; nt < 4; ++nt) \
    _Pragma("unroll") for (int ks = 0; ks < 2; ++ks) \
      b[nt][ks] = *(const f16x8*)&Bs[BB][bh][bOff[ks] + nt * 1024]; \
  } while (0)
#define MFMA_ROW(SLOT, ROW) do { \
    _Pragma("unroll") for (int nt = 0; nt < 4; ++nt) \
    _Pragma("unroll") for (int ks = 0; ks < 2; ++ks) \
      acc[ROW][nt] = __builtin_amdgcn_mfma_f32_16x16x32_f16( \
          a[SLOT][ks], b[nt][ks], acc[ROW][nt], 0, 0, 0); \
  } while (0)

#define CFENCE asm volatile("" ::: "memory")
#define WAIT_VM8 asm volatile("s_waitcnt vmcnt(8)" ::: "memory")
#define WAIT_VM0 asm volatile("s_waitcnt vmcnt(0)" ::: "memory")
#define BAR __builtin_amdgcn_s_barrier()
#define SCHED0 __builtin_amdgcn_sched_barrier(0)
#define SETP1 __builtin_amdgcn_s_setprio(1)
#define SETP0 __builtin_amdgcn_s_setprio(0)

#define KTILE(BA, BB, SA, SB, TAILWAIT) do { \
    CFENCE; \
    /* alpha */ \
    SA; \
    READ_B(BB); \
    READ_A1(BA, 0, 0); READ_A1(BA, 1, 1); \
    SETP1; \
    MFMA_ROW(0, 0); \
    READ_A1(BA, 2, 2); \
    MFMA_ROW(1, 1); \
    READ_A1(BA, 3, 3); \
    MFMA_ROW(2, 2); \
    MFMA_ROW(3, 3); \
    SETP0; \
    SCHED0; BAR; CFENCE; \
    /* beta */ \
    SB; \
    READ_A1(BA, 0, 4); READ_A1(BA, 1, 5); \
    SETP1; \
    MFMA_ROW(0, 4); \
    READ_A1(BA, 2, 6); \
    MFMA_ROW(1, 5); \
    READ_A1(BA, 3, 7); \
    MFMA_ROW(2, 6); \
    MFMA_ROW(3, 7); \
    SETP0; \
    TAILWAIT; SCHED0; BAR; \
  } while (0)

  // prologue: A(0)->As0, B(0)->Bs0, A(1)->As1, B(1)->Bs1 = 16 issues;
  // vmcnt(8) retires the first 8 (A0,B0) in-order; BAR publishes.
  SA2(0, 0); SB2(0, 0);
  SA2(1, 1); SB2(1, 1);
  WAIT_VM8;
  BAR;

  // main loop: 18 tiles, unrolled x6 so As-index (t%3) / Bs-index (t%2) and
  // stage targets ((t+2)%3 / t%2) are compile-time literals.
  for (int kt = 0; kt < NKT - 2; kt += 6) {
    KTILE(0, 0, SA2(2, kt + 2), SB2(0, kt + 2), WAIT_VM8);   // t = kt+0
    KTILE(1, 1, SA2(0, kt + 3), SB2(1, kt + 3), WAIT_VM8);   // t = kt+1
    KTILE(2, 0, SA2(1, kt + 4), SB2(0, kt + 4), WAIT_VM8);   // t = kt+2
    KTILE(0, 1, SA2(2, kt + 5), SB2(1, kt + 5), WAIT_VM8);   // t = kt+3
    KTILE(1, 0, SA2(0, kt + 6), SB2(0, kt + 6), WAIT_VM8);   // t = kt+4
    KTILE(2, 1, SA2(1, kt + 7), SB2(1, kt + 7), WAIT_VM8);   // t = kt+5
  }
  // t=18 (A buf 0, B buf 0): nothing left to stage; drain A(19),B(19)
  KTILE(0, 0, (void)0, (void)0, WAIT_VM0);
  // t=19 (A buf 1, B buf 1): bare
  KTILE(1, 1, (void)0, (void)0, (void)0);

#undef KTILE
#undef STAGE_A
#undef STAGE_B
#undef SA2
#undef SB2
#undef READ_A1
#undef READ_B
#undef MFMA_ROW

  // epilogue: C/D layout col=lane&15, row=(lane>>4)*4+reg
  const int colBase = jBase + wn * 64 + lm;
  float vv[4], bb[4];
#pragma unroll
  for (int nt = 0; nt < 4; ++nt) {
    int j = colBase + nt * 16;
    vv[nt] = v[j];
    bb[nt] = bw[j];
  }
  const int gq = lane >> 4;
#pragma unroll
  for (int mt = 0; mt < 8; ++mt) {
#pragma unroll
    for (int r = 0; r < 4; ++r) {
      float sumv = 0.f;
#pragma unroll
      for (int nt = 0; nt < 4; ++nt)
        sumv += tanh_fast(acc[mt][nt][r] + bb[nt]) * vv[nt];
      sumv += __shfl_xor(sumv, 1);
      sumv += __shfl_xor(sumv, 2);
      sumv += __shfl_xor(sumv, 4);
      sumv += __shfl_xor(sumv, 8);
      if (lm == 0) {
        int row = rowBase + wm * 128 + mt * 16 + gq * 4 + r;
        atomicAdd(&s[row], sumv);
      }
    }
  }
}

// ---- fused softmax + attention pooling ----
// grid (128 segs, 4 row-parts), block 320. Each block recomputes the segment
// softmax stats (m, z) from s (<=448 L2-hot floats), then pools its row part
// with att computed on the fly.  Partials go to pooled_parts[part] with
// plain float4 stores (no atomics); fold_kernel sums the 4 parts.
__global__ void softpool_kernel(const _Float16* __restrict__ F,
                                const float* __restrict__ s,
                                const int* __restrict__ segstart,
                                float* __restrict__ pooledp) {
  int seg = blockIdx.x, part = blockIdx.y;
  int st = segstart[seg], en = segstart[seg + 1];
  int t = threadIdx.x;
  __shared__ float redm[5], redz[5];
  float m = -1e30f;
  for (int i = st + t; i < en; i += 320) m = fmaxf(m, s[i]);
  for (int d = 1; d < 64; d <<= 1) m = fmaxf(m, __shfl_xor(m, d));
  if ((t & 63) == 0) redm[t >> 6] = m;
  __syncthreads();
  m = fmaxf(fmaxf(fmaxf(redm[0], redm[1]), fmaxf(redm[2], redm[3])), redm[4]);
  float z = 0.f;
  for (int i = st + t; i < en; i += 320) z += __expf(s[i] - m);
  for (int d = 1; d < 64; d <<= 1) z += __shfl_xor(z, d);
  if ((t & 63) == 0) redz[t >> 6] = z;
  __syncthreads();
  z = redz[0] + redz[1] + redz[2] + redz[3] + redz[4];
  float rz = 1.0f / z;

  int len = en - st;
  int chunk = (len + NPART - 1) / NPART;
  int r0 = st + chunk * part;
  int r1 = min(en, r0 + chunk);
  float acc[4] = {0.f, 0.f, 0.f, 0.f};
  int r = r0;
  for (; r + 2 <= r1; r += 2) {
    float a0 = __expf(s[r] - m) * rz;
    float a1 = __expf(s[r + 1] - m) * rz;
    f16x4 f0 = ((const f16x4*)(F + (size_t)r * DIM))[t];
    f16x4 f1 = ((const f16x4*)(F + (size_t)(r + 1) * DIM))[t];
#pragma unroll
    for (int c = 0; c < 4; ++c) {
      acc[c] = fmaf(a0, (float)f0[c], acc[c]);
      acc[c] = fmaf(a1, (float)f1[c], acc[c]);
    }
  }
  if (r < r1) {
    float a0 = __expf(s[r] - m) * rz;
    f16x4 f0 = ((const f16x4*)(F + (size_t)r * DIM))[t];
#pragma unroll
    for (int c = 0; c < 4; ++c) acc[c] = fmaf(a0, (float)f0[c], acc[c]);
  }
  float4 o;
  o.x = acc[0]; o.y = acc[1]; o.z = acc[2]; o.w = acc[3];
  *(float4*)(pooledp + ((size_t)part * NSEG + seg) * DIM + t * 4) = o;
}

// ---- fold the 4 softpool partials: pooled = sum_p pooled_parts[p] ----
__global__ void fold_kernel(const float* __restrict__ pp,
                            float* __restrict__ pooled) {
  int i = blockIdx.x * 256 + threadIdx.x;   // over NSEG*DIM = 163840
  pooled[i] = pp[i] + pp[i + NSEG * DIM] + pp[i + 2 * NSEG * DIM] +
              pp[i + 3 * NSEG * DIM];
}

// ---- head layer 1: h = relu(pooled @ W1^T + b1), [128,512] ----
__global__ void head1_kernel(const float* __restrict__ pooled,
                             const float* __restrict__ W1,
                             const float* __restrict__ b1, float* __restrict__ h) {
  int og = blockIdx.x, sg = blockIdx.y;
  __shared__ float Wt[16 * 65];
  __shared__ float Pt[32 * 65];
  int t = threadIdx.x;
  int tx = t & 15, ty = t >> 4;
  float acc0 = 0.f, acc1 = 0.f;
  for (int kcc = 0; kcc < 20; ++kcc) {
    __syncthreads();
#pragma unroll
    for (int u = 0; u < 4; ++u) {
      int lin = t + 256 * u;
      int o = lin >> 6, kk = lin & 63;
      Wt[o * 65 + kk] = W1[(size_t)(og * 16 + o) * DIM + kcc * 64 + kk];
    }
#pragma unroll
    for (int u = 0; u < 8; ++u) {
      int lin = t + 256 * u;
      int ss = lin >> 6, kk = lin & 63;
      Pt[ss * 65 + kk] = pooled[(size_t)(sg * 32 + ss) * DIM + kcc * 64 + kk];
    }
    __syncthreads();
#pragma unroll
    for (int kk = 0; kk < 64; ++kk) {
      float wv = Wt[tx * 65 + kk];
      acc0 = fmaf(Pt[ty * 65 + kk], wv, acc0);
      acc1 = fmaf(Pt[(ty + 16) * 65 + kk], wv, acc1);
    }
  }
  int o = og * 16 + tx;
  float bias = b1[o];
  h[(size_t)(sg * 32 + ty) * DHEAD + o] = fmaxf(acc0 + bias, 0.f);
  h[(size_t)(sg * 32 + ty + 16) * DHEAD + o] = fmaxf(acc1 + bias, 0.f);
}

// ---- head layer 2: out[seg] = relu_h[seg] . W2 + b2 ----
__global__ void head2_kernel(const float* __restrict__ h,
                             const float* __restrict__ W2,
                             const float* __restrict__ b2, float* __restrict__ out) {
  int seg = blockIdx.x;
  int t = threadIdx.x;
  float val = h[(size_t)seg * DHEAD + t] * W2[t] +
              h[(size_t)seg * DHEAD + t + 256] * W2[t + 256];
  for (int d = 1; d < 64; d <<= 1) val += __shfl_xor(val, d);
  __shared__ float red[4];
  if ((t & 63) == 0) red[t >> 6] = val;
  __syncthreads();
  if (t == 0) out[seg] = red[0] + red[1] + red[2] + red[3] + b2[0];
}

extern "C" void kernel_launch(void* const* d_in, const int* in_sizes, int n_in,
                              void* d_out, int out_size, void* d_ws, size_t ws_size,
                              hipStream_t stream) {
  const float* features = (const float*)d_in[0];
  const float* Ww = (const float*)d_in[1];
  const float* bw = (const float*)d_in[2];
  const float* v = (const float*)d_in[3];
  const float* W1 = (const float*)d_in[4];
  const float* b1 = (const float*)d_in[5];
  const float* W2 = (const float*)d_in[6];
  const float* b2 = (const float*)d_in[7];
  const int* segids = (const int*)d_in[8];
  float* out = (float*)d_out;

  char* ws = (char*)d_ws;
  _Float16* Xh = (_Float16*)(ws + OFF_XH);
  _Float16* Wh = (_Float16*)(ws + OFF_WH);
  float* s = (float*)(ws + OFF_S);
  int* segstart = (int*)(ws + OFF_SEG);
  float* pooled = (float*)(ws + OFF_POOL);
  float* pooledp = (float*)(ws + OFF_PP);   // aliases Wh (dead after gemm)
  float* h = (float*)(ws + OFF_H);

  const int na8 = TOTAL_ROWS * DIM / 8;   // 5242880
  const int nb8 = DIM * DIM / 8;          // 204800
  cvt_init_kernel<<<(na8 + nb8 + 255) / 256, 256, 0, stream>>>(
      features, Xh, na8, Ww, Wh, nb8, segids, segstart, s);

  dim3 ggrid(TOTAL_ROWS / 256, DIM / 256);   // (128, 5)
  gemm_s_kernel<<<ggrid, 512, 0, stream>>>(Xh, Wh, v, bw, s);

  softpool_kernel<<<dim3(NSEG, NPART), 320, 0, stream>>>(Xh, s, segstart, pooledp);
  fold_kernel<<<NSEG * DIM / 256, 256, 0, stream>>>(pooledp, pooled);
  head1_kernel<<<dim3(32, 4), 256, 0, stream>>>(pooled, W1, b1, h);
  head2_kernel<<<NSEG, 256, 0, stream>>>(h, W2, b2, out);
}